// Round 5
// baseline (737.804 us; speedup 1.0000x reference)
//
#include <hip/hip_runtime.h>
#include <hip/hip_bf16.h>
#include <math.h>

// Problem: B=64, T=1024, H=1024. M = B*T = 65536 score rows.
// out = [context (64*1024 fp32)] ++ [weights (64*1024 fp32)]
// ws fast path: [scores_p 4x64K f32 = 1MB][dec 256KB][W_bf16 2MB][A_bf16 128MB]

typedef __attribute__((ext_vector_type(8))) short bf16x8;
typedef __attribute__((ext_vector_type(8))) unsigned short ushort8;
typedef __attribute__((ext_vector_type(4))) float f32x4;

__device__ __forceinline__ unsigned short f2bf(float f) {
  union { float f; unsigned int u; } v; v.f = f;
  unsigned int r = v.u + 0x7FFFu + ((v.u >> 16) & 1u);  // RNE
  return (unsigned short)(r >> 16);
}

__device__ __forceinline__ float bf2f(unsigned short b) {
  union { unsigned int u; float f; } v; v.u = ((unsigned int)b) << 16;
  return v.f;
}

__device__ __forceinline__ float fast_tanh(float x) {
  float e = __expf(2.0f * x);
  return 1.0f - 2.0f / (e + 1.0f);  // saturates correctly at +-1
}

__device__ __forceinline__ void gld16(const void* g, void* l) {
  __builtin_amdgcn_global_load_lds(
      (const __attribute__((address_space(1))) void*)g,
      (__attribute__((address_space(3))) void*)l, 16, 0, 0);
}

// ===== fused prep kernel: W-cvt | A-cvt | dec-GEMV ============================
__global__ __launch_bounds__(256) void prep_kernel(
    const float* __restrict__ spatial, const float* __restrict__ hidden,
    const float* __restrict__ W_enc, const float* __restrict__ b_enc,
    const float* __restrict__ W_dec, const float* __restrict__ b_dec,
    unsigned short* __restrict__ Wbf, unsigned short* __restrict__ Abf,
    float* __restrict__ dec, int nW, int nA) {
  __shared__ float hs[1024];
  const int bid = blockIdx.x, tid = threadIdx.x;
  if (bid < nW + nA) {
    const float* src = (bid < nW) ? W_enc : spatial;
    unsigned short* dst = (bid < nW) ? Wbf : Abf;
    size_t g4 = (size_t)(bid < nW ? bid : bid - nW) * 256 + tid;
    float4 v = ((const float4*)src)[g4];
    ushort4 o;
    o.x = f2bf(v.x); o.y = f2bf(v.y); o.z = f2bf(v.z); o.w = f2bf(v.w);
    *(ushort4*)(dst + g4 * 4) = o;
    return;
  }
  const int dbid = bid - nW - nA;             // 0..511
  const int b = dbid >> 3, o0 = (dbid & 7) * 128;
  const int wave = tid >> 6, lane = tid & 63;
  ((float4*)hs)[tid] = ((const float4*)(hidden + (size_t)b * 1024))[tid];
  __syncthreads();
  for (int it = 0; it < 32; it++) {
    int o = o0 + it * 4 + wave;
    const float4* w4 = (const float4*)(W_dec + (size_t)o * 1024);
    float4 acc; acc.x = acc.y = acc.z = acc.w = 0.f;
    #pragma unroll
    for (int j = 0; j < 4; j++) {
      int i = j * 64 + lane;
      float4 x = ((const float4*)hs)[i], y = w4[i];
      acc.x = fmaf(x.x, y.x, acc.x);
      acc.y = fmaf(x.y, y.y, acc.y);
      acc.z = fmaf(x.z, y.z, acc.z);
      acc.w = fmaf(x.w, y.w, acc.w);
    }
    float v = (acc.x + acc.y) + (acc.z + acc.w);
    #pragma unroll
    for (int off = 1; off < 64; off <<= 1) v += __shfl_xor(v, off);
    if (lane == 0) dec[b * 1024 + o] = v + b_dec[o] + b_enc[o];
  }
}

// ======== FAST PATH: bf16 GEMM + tanh + w_score reduce ========================
// A staged via gld16 into 8 KB LDS; B FRAGMENTS LOADED DIRECTLY FROM GLOBAL
// (W_enc bf16 = 2 MB, fully L2-resident) -> halves LDS read traffic per MFMA.
// Block owns m-tile (128 rows) x 4 n-tiles (nh half), score partials in regs.
__global__ __launch_bounds__(256) void enc_score_bf16_kernel(
    const unsigned short* __restrict__ A,   // bf16 bits [65536,1024]
    const unsigned short* __restrict__ W,   // bf16 bits [1024,1024]
    const float* __restrict__ dec,          // [64,1024] (b_dec+b_enc folded)
    const float* __restrict__ w_score,
    float* __restrict__ scores_p)           // [4][65536]
{
  __shared__ unsigned short As[128 * 32];   // 8 KB

  const int bid = blockIdx.x;
  const int m_tile = (bid >> 4) * 8 + (bid & 7);
  const int nh = (bid >> 3) & 1;
  const int m0 = m_tile * 128;
  const int tid = threadIdx.x;
  const int lane = tid & 63, wave = tid >> 6;
  const int wm = (wave >> 1) * 64, wn = (wave & 1) * 64;
  const int quad = lane >> 4, colL = lane & 15;

  const int srow = wave * 32 + (lane >> 2);
  const int scol = (lane & 3) * 8;
  const unsigned short* ga = A + (size_t)(m0 + srow) * 1024 + scol;
  unsigned short* la = As + wave * 1024;

  const int b = m0 >> 10;
  float rs[4][4];
  #pragma unroll
  for (int mi = 0; mi < 4; mi++)
    #pragma unroll
    for (int r = 0; r < 4; r++) rs[mi][r] = 0.f;

  for (int nt = 0; nt < 4; nt++) {
    const int n0 = (nh * 4 + nt) * 128;
    // per-lane B base: row = n0 + wn + colL (+ i*16), k-window = quad*8 (+ k0)
    const unsigned short* gw = W + (size_t)(n0 + wn + colL) * 1024 + quad * 8;

    f32x4 acc[4][4];
    #pragma unroll
    for (int mi = 0; mi < 4; mi++)
      #pragma unroll
      for (int ni = 0; ni < 4; ni++)
        acc[mi][ni] = (f32x4){0.f, 0.f, 0.f, 0.f};

    for (int k0 = 0; k0 < 1024; k0 += 32) {
      // A -> LDS (async, barrier-coupled)
      gld16(ga + k0,             la);
      gld16(ga + k0 + 16 * 1024, la + 512);
      // B frags from global/L2 — issued before the barrier; completed by its
      // vmcnt(0) drain, so no exposed latency at the MFMA.
      bf16x8 bfr[4];
      #pragma unroll
      for (int i = 0; i < 4; i++)
        bfr[i] = *(const bf16x8*)(gw + (size_t)(i * 16) * 1024 + k0);
      __syncthreads();
      bf16x8 af[4];
      #pragma unroll
      for (int i = 0; i < 4; i++)
        af[i] = *(const bf16x8*)(As + (wm + i * 16 + colL) * 32 + quad * 8);
      #pragma unroll
      for (int mi = 0; mi < 4; mi++)
        #pragma unroll
        for (int ni = 0; ni < 4; ni++)
          acc[mi][ni] = __builtin_amdgcn_mfma_f32_16x16x32_bf16(
              af[mi], bfr[ni], acc[mi][ni], 0, 0, 0);
      __syncthreads();
    }

    float decv[4], wsv[4];
    #pragma unroll
    for (int ni = 0; ni < 4; ni++) {
      int n = n0 + wn + ni * 16 + colL;
      decv[ni] = dec[b * 1024 + n];
      wsv[ni] = w_score[n];
    }
    #pragma unroll
    for (int mi = 0; mi < 4; mi++)
      #pragma unroll
      for (int ni = 0; ni < 4; ni++)
        #pragma unroll
        for (int r = 0; r < 4; r++)
          rs[mi][r] += fast_tanh(acc[mi][ni][r] + decv[ni]) * wsv[ni];
  }

  const int slot = nh * 2 + (wave & 1);
  #pragma unroll
  for (int mi = 0; mi < 4; mi++)
    #pragma unroll
    for (int r = 0; r < 4; r++) {
      float v = rs[mi][r];
      v += __shfl_xor(v, 1);
      v += __shfl_xor(v, 2);
      v += __shfl_xor(v, 4);
      v += __shfl_xor(v, 8);
      if (colL == 0)
        scores_p[slot * 65536 + m0 + wm + mi * 16 + quad * 4 + r] = v;
    }
}

// ======== FALLBACK (ws too small): fused fp32-staging GEMM ====================
__global__ __launch_bounds__(256) void enc_score_f32_kernel(
    const float* __restrict__ A, const float* __restrict__ W,
    const float* __restrict__ dec, const float* __restrict__ w_score,
    float* __restrict__ scores_p) {
  __shared__ unsigned short As[128][32];
  __shared__ unsigned short Bs[128][32];
  const int bid = blockIdx.x;
  const int n0 = (bid & 7) * 128;
  const int m0 = (bid >> 3) * 128;
  const int tid = threadIdx.x;
  const int lane = tid & 63, wave = tid >> 6;
  const int wm = (wave >> 1) * 64, wn = (wave & 1) * 64;
  const int quad = lane >> 4, colL = lane & 15;
  const int srow = tid >> 3;
  const int scol = (tid & 7) * 4;
  f32x4 acc[4][4];
  #pragma unroll
  for (int mi = 0; mi < 4; mi++)
    #pragma unroll
    for (int ni = 0; ni < 4; ni++)
      acc[mi][ni] = (f32x4){0.f, 0.f, 0.f, 0.f};
  for (int k0 = 0; k0 < 1024; k0 += 32) {
    #pragma unroll
    for (int p = 0; p < 4; p++) {
      int r = p * 32 + srow;
      float4 va = *(const float4*)(A + (size_t)(m0 + r) * 1024 + (k0 + scol));
      float4 vb = *(const float4*)(W + (size_t)(n0 + r) * 1024 + (k0 + scol));
      ushort4 pa, pb;
      pa.x = f2bf(va.x); pa.y = f2bf(va.y); pa.z = f2bf(va.z); pa.w = f2bf(va.w);
      pb.x = f2bf(vb.x); pb.y = f2bf(vb.y); pb.z = f2bf(vb.z); pb.w = f2bf(vb.w);
      *(ushort4*)(&As[r][scol]) = pa;
      *(ushort4*)(&Bs[r][scol]) = pb;
    }
    __syncthreads();
    bf16x8 af[4], bfr[4];
    #pragma unroll
    for (int i = 0; i < 4; i++) {
      af[i]  = *(const bf16x8*)(&As[wm + i * 16 + colL][quad * 8]);
      bfr[i] = *(const bf16x8*)(&Bs[wn + i * 16 + colL][quad * 8]);
    }
    #pragma unroll
    for (int mi = 0; mi < 4; mi++)
      #pragma unroll
      for (int ni = 0; ni < 4; ni++)
        acc[mi][ni] = __builtin_amdgcn_mfma_f32_16x16x32_bf16(
            af[mi], bfr[ni], acc[mi][ni], 0, 0, 0);
    __syncthreads();
  }
  const int b = m0 >> 10;
  float decv[4], wsv[4];
  #pragma unroll
  for (int ni = 0; ni < 4; ni++) {
    int n = n0 + wn + ni * 16 + colL;
    decv[ni] = dec[b * 1024 + n];
    wsv[ni] = w_score[n];
  }
  #pragma unroll
  for (int mi = 0; mi < 4; mi++) {
    float rsv[4] = {0.f, 0.f, 0.f, 0.f};
    #pragma unroll
    for (int ni = 0; ni < 4; ni++)
      #pragma unroll
      for (int r = 0; r < 4; r++)
        rsv[r] += fast_tanh(acc[mi][ni][r] + decv[ni]) * wsv[ni];
    #pragma unroll
    for (int r = 0; r < 4; r++) {
      float v = rsv[r];
      v += __shfl_xor(v, 1);
      v += __shfl_xor(v, 2);
      v += __shfl_xor(v, 4);
      v += __shfl_xor(v, 8);
      if (colL == 0)
        atomicAdd(&scores_p[m0 + wm + mi * 16 + quad * 4 + r], v);
    }
  }
}

// ------- softmax over T per batch; sums 4 partial slots; zeros context --------
__global__ void softmax_kernel(const float* __restrict__ scores_p,
                               float* __restrict__ weights,
                               float* __restrict__ context) {
  __shared__ float red[256];
  int b = blockIdx.x, tid = threadIdx.x;
  float4 z; z.x = z.y = z.z = z.w = 0.f;
  ((float4*)context)[blockIdx.x * 256 + tid] = z;
  float v[4];
  float mx = -1e30f;
  #pragma unroll
  for (int i = 0; i < 4; i++) {
    int m = b * 1024 + tid + i * 256;
    v[i] = scores_p[m] + scores_p[65536 + m] + scores_p[2 * 65536 + m] +
           scores_p[3 * 65536 + m];
    mx = fmaxf(mx, v[i]);
  }
  red[tid] = mx; __syncthreads();
  for (int off = 128; off > 0; off >>= 1) {
    if (tid < off) red[tid] = fmaxf(red[tid], red[tid + off]);
    __syncthreads();
  }
  mx = red[0]; __syncthreads();
  float sum = 0.f;
  #pragma unroll
  for (int i = 0; i < 4; i++) { v[i] = __expf(v[i] - mx); sum += v[i]; }
  red[tid] = sum; __syncthreads();
  for (int off = 128; off > 0; off >>= 1) {
    if (tid < off) red[tid] += red[tid + off];
    __syncthreads();
  }
  float inv = 1.0f / red[0];
  #pragma unroll
  for (int i = 0; i < 4; i++) weights[b * 1024 + tid + i * 256] = v[i] * inv;
}

// -------- context[b,h] = sum_t spatial[b,t,h] * weights[b,t]  (bf16 A) --------
__global__ void context_bf16_kernel(const unsigned short* __restrict__ Abf,
                                    const float* __restrict__ weights,
                                    float* __restrict__ context) {
  int b = blockIdx.x >> 3, tq = blockIdx.x & 7;
  int tid = threadIdx.x;
  __shared__ float wl[128];
  __shared__ float cs[128 * 8];
  if (tid < 128) wl[tid] = weights[b * 1024 + tq * 128 + tid];
  __syncthreads();
  const int hl = tid & 127, p = tid >> 7;   // 128 h-groups x 2 row parities
  const int h0 = hl * 8;
  const unsigned short* sp =
      Abf + ((size_t)(b * 1024 + tq * 128 + p)) * 1024 + h0;
  float acc[8];
  #pragma unroll
  for (int j = 0; j < 8; j++) acc[j] = 0.f;
  for (int t = 0; t < 128; t += 2) {
    float w = wl[t + p];
    ushort8 x = *(const ushort8*)(sp + (size_t)t * 1024);
    #pragma unroll
    for (int j = 0; j < 8; j++) acc[j] = fmaf(w, bf2f(x[j]), acc[j]);
  }
  if (p == 0) {
    #pragma unroll
    for (int j = 0; j < 8; j++) cs[hl * 8 + j] = acc[j];
  }
  __syncthreads();
  if (p == 1) {
    #pragma unroll
    for (int j = 0; j < 8; j++) cs[hl * 8 + j] += acc[j];
  }
  __syncthreads();
  if (p == 0) {
    #pragma unroll
    for (int j = 0; j < 8; j++)
      atomicAdd(&context[b * 1024 + h0 + j], cs[hl * 8 + j]);
  }
}

// fp32 context for fallback path
__global__ void context_f32_kernel(const float* __restrict__ spatial,
                                   const float* __restrict__ weights,
                                   float* __restrict__ context) {
  int b = blockIdx.x >> 3, tq = blockIdx.x & 7;
  int tid = threadIdx.x;
  __shared__ float wl[128];
  if (tid < 128) wl[tid] = weights[b * 1024 + tq * 128 + tid];
  __syncthreads();
  const float4* sp =
      (const float4*)(spatial + ((size_t)(b * 1024 + tq * 128)) * 1024);
  float4 acc; acc.x = acc.y = acc.z = acc.w = 0.f;
  #pragma unroll 4
  for (int t = 0; t < 128; t++) {
    float w = wl[t];
    float4 x = sp[(size_t)t * 256 + tid];
    acc.x = fmaf(w, x.x, acc.x);
    acc.y = fmaf(w, x.y, acc.y);
    acc.z = fmaf(w, x.z, acc.z);
    acc.w = fmaf(w, x.w, acc.w);
  }
  float* c = context + b * 1024 + tid * 4;
  atomicAdd(c + 0, acc.x);
  atomicAdd(c + 1, acc.y);
  atomicAdd(c + 2, acc.z);
  atomicAdd(c + 3, acc.w);
}

extern "C" void kernel_launch(void* const* d_in, const int* in_sizes, int n_in,
                              void* d_out, int out_size, void* d_ws, size_t ws_size,
                              hipStream_t stream) {
  const float* spatial  = (const float*)d_in[0];  // [64,1024,1024]
  const float* hidden   = (const float*)d_in[1];  // [64,1024]
  const float* W_enc    = (const float*)d_in[2];  // [1024,1024]
  const float* b_enc    = (const float*)d_in[3];  // [1024]
  const float* W_dec    = (const float*)d_in[4];  // [1024,1024]
  const float* b_dec    = (const float*)d_in[5];  // [1024]
  const float* w_score  = (const float*)d_in[6];  // [1024]
  // d_in[7] = b_score: softmax shift-invariant, unused.

  float* out      = (float*)d_out;
  float* context  = out;            // 65536 floats
  float* weights  = out + 65536;    // 65536 floats

  float* scores_p = (float*)d_ws;                            // 4*64K f32 @ 0
  float* dec      = scores_p + 4 * 65536;                    // 64K f32 @ 1MB
  unsigned short* Wbf = (unsigned short*)(dec + 65536);      // 1M  @ 1.25MB
  unsigned short* Abf = Wbf + 1024 * 1024;                   // 64M @ 3.25MB

  const size_t need =
      4ull * 65536 * 4 + 65536 * 4 + 2ull * 1024 * 1024 + 2ull * 65536 * 1024;

  if (ws_size >= need) {
    const int nW = 1024, nA = 65536;
    prep_kernel<<<nW + nA + 512, 256, 0, stream>>>(
        spatial, hidden, W_enc, b_enc, W_dec, b_dec, Wbf, Abf, dec, nW, nA);
    enc_score_bf16_kernel<<<1024, 256, 0, stream>>>(Abf, Wbf, dec, w_score,
                                                    scores_p);
    softmax_kernel<<<64, 256, 0, stream>>>(scores_p, weights, context);
    context_bf16_kernel<<<512, 256, 0, stream>>>(Abf, weights, context);
  } else {
    hipMemsetAsync(scores_p, 0, 4 * 65536 * sizeof(float), stream);
    prep_kernel<<<512, 256, 0, stream>>>(
        spatial, hidden, W_enc, b_enc, W_dec, b_dec, nullptr, nullptr, dec,
        0, 0);
    enc_score_f32_kernel<<<4096, 256, 0, stream>>>(spatial, W_enc, dec,
                                                   w_score, scores_p);
    softmax_kernel<<<64, 256, 0, stream>>>(scores_p, weights, context);
    context_f32_kernel<<<512, 256, 0, stream>>>(spatial, weights, context);
  }
}

// Round 6
// 636.117 us; speedup vs baseline: 1.1599x; 1.1599x over previous
//
#include <hip/hip_runtime.h>
#include <hip/hip_bf16.h>
#include <math.h>

// Problem: B=64, T=1024, H=1024. M = B*T = 65536 score rows.
// out = [context (64*1024 fp32)] ++ [weights (64*1024 fp32)]
// ws fast path: [scores_p 16x64K f32 = 4MB][dec 256KB][W_bf16 2MB][A_bf16 128MB]

typedef __attribute__((ext_vector_type(8))) short bf16x8;
typedef __attribute__((ext_vector_type(8))) unsigned short ushort8;
typedef __attribute__((ext_vector_type(4))) float f32x4;

__device__ __forceinline__ unsigned short f2bf(float f) {
  union { float f; unsigned int u; } v; v.f = f;
  unsigned int r = v.u + 0x7FFFu + ((v.u >> 16) & 1u);  // RNE
  return (unsigned short)(r >> 16);
}

__device__ __forceinline__ float bf2f(unsigned short b) {
  union { unsigned int u; float f; } v; v.u = ((unsigned int)b) << 16;
  return v.f;
}

__device__ __forceinline__ float fast_tanh(float x) {
  float e = __expf(2.0f * x);
  return 1.0f - 2.0f / (e + 1.0f);  // saturates correctly at +-1
}

__device__ __forceinline__ void gld16(const void* g, void* l) {
  __builtin_amdgcn_global_load_lds(
      (const __attribute__((address_space(1))) void*)g,
      (__attribute__((address_space(3))) void*)l, 16, 0, 0);
}

// ===== fused prep kernel: W-cvt | A-cvt | dec-GEMV ============================
__global__ __launch_bounds__(256) void prep_kernel(
    const float* __restrict__ spatial, const float* __restrict__ hidden,
    const float* __restrict__ W_enc, const float* __restrict__ b_enc,
    const float* __restrict__ W_dec, const float* __restrict__ b_dec,
    unsigned short* __restrict__ Wbf, unsigned short* __restrict__ Abf,
    float* __restrict__ dec, int nW, int nA) {
  __shared__ float hs[1024];
  const int bid = blockIdx.x, tid = threadIdx.x;
  if (bid < nW + nA) {
    const float* src = (bid < nW) ? W_enc : spatial;
    unsigned short* dst = (bid < nW) ? Wbf : Abf;
    size_t g4 = (size_t)(bid < nW ? bid : bid - nW) * 256 + tid;
    float4 v = ((const float4*)src)[g4];
    ushort4 o;
    o.x = f2bf(v.x); o.y = f2bf(v.y); o.z = f2bf(v.z); o.w = f2bf(v.w);
    *(ushort4*)(dst + g4 * 4) = o;
    return;
  }
  const int dbid = bid - nW - nA;             // 0..511
  const int b = dbid >> 3, o0 = (dbid & 7) * 128;
  const int wave = tid >> 6, lane = tid & 63;
  ((float4*)hs)[tid] = ((const float4*)(hidden + (size_t)b * 1024))[tid];
  __syncthreads();
  for (int it = 0; it < 32; it++) {
    int o = o0 + it * 4 + wave;
    const float4* w4 = (const float4*)(W_dec + (size_t)o * 1024);
    float4 acc; acc.x = acc.y = acc.z = acc.w = 0.f;
    #pragma unroll
    for (int j = 0; j < 4; j++) {
      int i = j * 64 + lane;
      float4 x = ((const float4*)hs)[i], y = w4[i];
      acc.x = fmaf(x.x, y.x, acc.x);
      acc.y = fmaf(x.y, y.y, acc.y);
      acc.z = fmaf(x.z, y.z, acc.z);
      acc.w = fmaf(x.w, y.w, acc.w);
    }
    float v = (acc.x + acc.y) + (acc.z + acc.w);
    #pragma unroll
    for (int off = 1; off < 64; off <<= 1) v += __shfl_xor(v, off);
    if (lane == 0) dec[b * 1024 + o] = v + b_dec[o] + b_enc[o];
  }
}

// ======== FAST PATH: bf16 GEMM + tanh + w_score reduce (R2 structure) =========
// C[m,n] = sum_k A[m,k]*W[n,k]; tile 128x128, BK=32, 4 waves (2x2 of 64x64),
// A and B both staged via gld16 into 8KB LDS each (best-measured: R2, 242us).
// grid n-tile fastest (8 blocks share the A m-tile / XCD). Score partials go
// to per-(ntile,wave-n-half) slots -> no atomics, no pre-zero.
__global__ __launch_bounds__(256) void enc_score_bf16_kernel(
    const unsigned short* __restrict__ A,   // bf16 bits [65536,1024]
    const unsigned short* __restrict__ W,   // bf16 bits [1024,1024]
    const float* __restrict__ dec,          // [64,1024] (b_dec+b_enc folded)
    const float* __restrict__ w_score,
    float* __restrict__ scores_p)           // [16][65536]
{
  __shared__ unsigned short As[128 * 32];   // 8 KB
  __shared__ unsigned short Bs[128 * 32];   // 8 KB

  const int bid = blockIdx.x;
  const int n0 = (bid & 7) * 128;
  const int m0 = (bid >> 3) * 128;
  const int tid = threadIdx.x;
  const int lane = tid & 63, wave = tid >> 6;
  const int wm = (wave >> 1) * 64, wn = (wave & 1) * 64;
  const int quad = lane >> 4, colL = lane & 15;

  // staging: wave covers rows [wave*32, wave*32+32); lane l -> row +j*16+l/4,
  // col (l&3)*8 == LDS base + lane*16B (gld16 contiguity requirement).
  const int srow = wave * 32 + (lane >> 2);
  const int scol = (lane & 3) * 8;
  const unsigned short* ga = A + (size_t)(m0 + srow) * 1024 + scol;
  const unsigned short* gb = W + (size_t)(n0 + srow) * 1024 + scol;
  unsigned short* la = As + wave * 1024;
  unsigned short* lb = Bs + wave * 1024;

  f32x4 acc[4][4];
  #pragma unroll
  for (int mi = 0; mi < 4; mi++)
    #pragma unroll
    for (int ni = 0; ni < 4; ni++)
      acc[mi][ni] = (f32x4){0.f, 0.f, 0.f, 0.f};

  for (int k0 = 0; k0 < 1024; k0 += 32) {
    gld16(ga + k0,             la);
    gld16(ga + k0 + 16 * 1024, la + 512);
    gld16(gb + k0,             lb);
    gld16(gb + k0 + 16 * 1024, lb + 512);
    __syncthreads();
    bf16x8 af[4], bfr[4];
    #pragma unroll
    for (int i = 0; i < 4; i++) {
      af[i]  = *(const bf16x8*)(As + (wm + i * 16 + colL) * 32 + quad * 8);
      bfr[i] = *(const bf16x8*)(Bs + (wn + i * 16 + colL) * 32 + quad * 8);
    }
    #pragma unroll
    for (int mi = 0; mi < 4; mi++)
      #pragma unroll
      for (int ni = 0; ni < 4; ni++)
        acc[mi][ni] = __builtin_amdgcn_mfma_f32_16x16x32_bf16(
            af[mi], bfr[ni], acc[mi][ni], 0, 0, 0);
    __syncthreads();
  }

  // epilogue: tanh(enc + dec') * w_score, reduce over this wave's 64 n's,
  // store into slot (n-tile, wave-n-half) -- non-atomic.
  const int b = m0 >> 10;
  float decv[4], wsv[4];
  #pragma unroll
  for (int ni = 0; ni < 4; ni++) {
    int n = n0 + wn + ni * 16 + colL;
    decv[ni] = dec[b * 1024 + n];
    wsv[ni] = w_score[n];
  }
  const int slot = (bid & 7) * 2 + (wave & 1);
  #pragma unroll
  for (int mi = 0; mi < 4; mi++) {
    float rs[4] = {0.f, 0.f, 0.f, 0.f};
    #pragma unroll
    for (int ni = 0; ni < 4; ni++)
      #pragma unroll
      for (int r = 0; r < 4; r++)
        rs[r] += fast_tanh(acc[mi][ni][r] + decv[ni]) * wsv[ni];
    #pragma unroll
    for (int r = 0; r < 4; r++) {
      float v = rs[r];
      v += __shfl_xor(v, 1);
      v += __shfl_xor(v, 2);
      v += __shfl_xor(v, 4);
      v += __shfl_xor(v, 8);
      if (colL == 0)
        scores_p[slot * 65536 + m0 + wm + mi * 16 + quad * 4 + r] = v;
    }
  }
}

// ======== FALLBACK (ws too small): fused fp32-staging GEMM ====================
__global__ __launch_bounds__(256) void enc_score_f32_kernel(
    const float* __restrict__ A, const float* __restrict__ W,
    const float* __restrict__ dec, const float* __restrict__ w_score,
    float* __restrict__ scores_p) {
  __shared__ unsigned short As[128][32];
  __shared__ unsigned short Bs[128][32];
  const int bid = blockIdx.x;
  const int n0 = (bid & 7) * 128;
  const int m0 = (bid >> 3) * 128;
  const int tid = threadIdx.x;
  const int lane = tid & 63, wave = tid >> 6;
  const int wm = (wave >> 1) * 64, wn = (wave & 1) * 64;
  const int quad = lane >> 4, colL = lane & 15;
  const int srow = tid >> 3;
  const int scol = (tid & 7) * 4;
  f32x4 acc[4][4];
  #pragma unroll
  for (int mi = 0; mi < 4; mi++)
    #pragma unroll
    for (int ni = 0; ni < 4; ni++)
      acc[mi][ni] = (f32x4){0.f, 0.f, 0.f, 0.f};
  for (int k0 = 0; k0 < 1024; k0 += 32) {
    #pragma unroll
    for (int p = 0; p < 4; p++) {
      int r = p * 32 + srow;
      float4 va = *(const float4*)(A + (size_t)(m0 + r) * 1024 + (k0 + scol));
      float4 vb = *(const float4*)(W + (size_t)(n0 + r) * 1024 + (k0 + scol));
      ushort4 pa, pb;
      pa.x = f2bf(va.x); pa.y = f2bf(va.y); pa.z = f2bf(va.z); pa.w = f2bf(va.w);
      pb.x = f2bf(vb.x); pb.y = f2bf(vb.y); pb.z = f2bf(vb.z); pb.w = f2bf(vb.w);
      *(ushort4*)(&As[r][scol]) = pa;
      *(ushort4*)(&Bs[r][scol]) = pb;
    }
    __syncthreads();
    bf16x8 af[4], bfr[4];
    #pragma unroll
    for (int i = 0; i < 4; i++) {
      af[i]  = *(const bf16x8*)(&As[wm + i * 16 + colL][quad * 8]);
      bfr[i] = *(const bf16x8*)(&Bs[wn + i * 16 + colL][quad * 8]);
    }
    #pragma unroll
    for (int mi = 0; mi < 4; mi++)
      #pragma unroll
      for (int ni = 0; ni < 4; ni++)
        acc[mi][ni] = __builtin_amdgcn_mfma_f32_16x16x32_bf16(
            af[mi], bfr[ni], acc[mi][ni], 0, 0, 0);
    __syncthreads();
  }
  const int b = m0 >> 10;
  float decv[4], wsv[4];
  #pragma unroll
  for (int ni = 0; ni < 4; ni++) {
    int n = n0 + wn + ni * 16 + colL;
    decv[ni] = dec[b * 1024 + n];
    wsv[ni] = w_score[n];
  }
  const int slot = (bid & 7) * 2 + (wave & 1);
  #pragma unroll
  for (int mi = 0; mi < 4; mi++) {
    float rsv[4] = {0.f, 0.f, 0.f, 0.f};
    #pragma unroll
    for (int ni = 0; ni < 4; ni++)
      #pragma unroll
      for (int r = 0; r < 4; r++)
        rsv[r] += fast_tanh(acc[mi][ni][r] + decv[ni]) * wsv[ni];
    #pragma unroll
    for (int r = 0; r < 4; r++) {
      float v = rsv[r];
      v += __shfl_xor(v, 1);
      v += __shfl_xor(v, 2);
      v += __shfl_xor(v, 4);
      v += __shfl_xor(v, 8);
      if (colL == 0)
        scores_p[slot * 65536 + m0 + wm + mi * 16 + quad * 4 + r] = v;
    }
  }
}

// ------- softmax over T per batch; sums 16 partial slots; zeros context -------
__global__ void softmax_kernel(const float* __restrict__ scores_p,
                               float* __restrict__ weights,
                               float* __restrict__ context) {
  __shared__ float red[256];
  int b = blockIdx.x, tid = threadIdx.x;
  float4 z; z.x = z.y = z.z = z.w = 0.f;
  ((float4*)context)[blockIdx.x * 256 + tid] = z;
  float v[4];
  float mx = -1e30f;
  #pragma unroll
  for (int i = 0; i < 4; i++) {
    int m = b * 1024 + tid + i * 256;
    float s = 0.f;
    #pragma unroll
    for (int sl = 0; sl < 16; sl++) s += scores_p[sl * 65536 + m];
    v[i] = s;
    mx = fmaxf(mx, v[i]);
  }
  red[tid] = mx; __syncthreads();
  for (int off = 128; off > 0; off >>= 1) {
    if (tid < off) red[tid] = fmaxf(red[tid], red[tid + off]);
    __syncthreads();
  }
  mx = red[0]; __syncthreads();
  float sum = 0.f;
  #pragma unroll
  for (int i = 0; i < 4; i++) { v[i] = __expf(v[i] - mx); sum += v[i]; }
  red[tid] = sum; __syncthreads();
  for (int off = 128; off > 0; off >>= 1) {
    if (tid < off) red[tid] += red[tid + off];
    __syncthreads();
  }
  float inv = 1.0f / red[0];
  #pragma unroll
  for (int i = 0; i < 4; i++) weights[b * 1024 + tid + i * 256] = v[i] * inv;
}

// -------- context[b,h] = sum_t spatial[b,t,h] * weights[b,t]  (bf16 A) --------
__global__ void context_bf16_kernel(const unsigned short* __restrict__ Abf,
                                    const float* __restrict__ weights,
                                    float* __restrict__ context) {
  int b = blockIdx.x >> 3, tq = blockIdx.x & 7;
  int tid = threadIdx.x;
  __shared__ float wl[128];
  __shared__ float cs[128 * 8];
  if (tid < 128) wl[tid] = weights[b * 1024 + tq * 128 + tid];
  __syncthreads();
  const int hl = tid & 127, p = tid >> 7;   // 128 h-groups x 2 row parities
  const int h0 = hl * 8;
  const unsigned short* sp =
      Abf + ((size_t)(b * 1024 + tq * 128 + p)) * 1024 + h0;
  float acc[8];
  #pragma unroll
  for (int j = 0; j < 8; j++) acc[j] = 0.f;
  for (int t = 0; t < 128; t += 2) {
    float w = wl[t + p];
    ushort8 x = *(const ushort8*)(sp + (size_t)t * 1024);
    #pragma unroll
    for (int j = 0; j < 8; j++) acc[j] = fmaf(w, bf2f(x[j]), acc[j]);
  }
  if (p == 0) {
    #pragma unroll
    for (int j = 0; j < 8; j++) cs[hl * 8 + j] = acc[j];
  }
  __syncthreads();
  if (p == 1) {
    #pragma unroll
    for (int j = 0; j < 8; j++) cs[hl * 8 + j] += acc[j];
  }
  __syncthreads();
  if (p == 0) {
    #pragma unroll
    for (int j = 0; j < 8; j++)
      atomicAdd(&context[b * 1024 + h0 + j], cs[hl * 8 + j]);
  }
}

// fp32 context for fallback path
__global__ void context_f32_kernel(const float* __restrict__ spatial,
                                   const float* __restrict__ weights,
                                   float* __restrict__ context) {
  int b = blockIdx.x >> 3, tq = blockIdx.x & 7;
  int tid = threadIdx.x;
  __shared__ float wl[128];
  if (tid < 128) wl[tid] = weights[b * 1024 + tq * 128 + tid];
  __syncthreads();
  const float4* sp =
      (const float4*)(spatial + ((size_t)(b * 1024 + tq * 128)) * 1024);
  float4 acc; acc.x = acc.y = acc.z = acc.w = 0.f;
  #pragma unroll 4
  for (int t = 0; t < 128; t++) {
    float w = wl[t];
    float4 x = sp[(size_t)t * 256 + tid];
    acc.x = fmaf(w, x.x, acc.x);
    acc.y = fmaf(w, x.y, acc.y);
    acc.z = fmaf(w, x.z, acc.z);
    acc.w = fmaf(w, x.w, acc.w);
  }
  float* c = context + b * 1024 + tid * 4;
  atomicAdd(c + 0, acc.x);
  atomicAdd(c + 1, acc.y);
  atomicAdd(c + 2, acc.z);
  atomicAdd(c + 3, acc.w);
}

extern "C" void kernel_launch(void* const* d_in, const int* in_sizes, int n_in,
                              void* d_out, int out_size, void* d_ws, size_t ws_size,
                              hipStream_t stream) {
  const float* spatial  = (const float*)d_in[0];  // [64,1024,1024]
  const float* hidden   = (const float*)d_in[1];  // [64,1024]
  const float* W_enc    = (const float*)d_in[2];  // [1024,1024]
  const float* b_enc    = (const float*)d_in[3];  // [1024]
  const float* W_dec    = (const float*)d_in[4];  // [1024,1024]
  const float* b_dec    = (const float*)d_in[5];  // [1024]
  const float* w_score  = (const float*)d_in[6];  // [1024]
  // d_in[7] = b_score: softmax shift-invariant, unused.

  float* out      = (float*)d_out;
  float* context  = out;            // 65536 floats
  float* weights  = out + 65536;    // 65536 floats

  float* scores_p = (float*)d_ws;                            // 16*64K f32 @ 0
  float* dec      = scores_p + 16 * 65536;                   // 64K f32 @ 4MB
  unsigned short* Wbf = (unsigned short*)(dec + 65536);      // 1M  @ 4.25MB
  unsigned short* Abf = Wbf + 1024 * 1024;                   // 64M @ 6.25MB

  const size_t need =
      16ull * 65536 * 4 + 65536 * 4 + 2ull * 1024 * 1024 + 2ull * 65536 * 1024;

  if (ws_size >= need) {
    const int nW = 1024, nA = 65536;
    prep_kernel<<<nW + nA + 512, 256, 0, stream>>>(
        spatial, hidden, W_enc, b_enc, W_dec, b_dec, Wbf, Abf, dec, nW, nA);
    enc_score_bf16_kernel<<<4096, 256, 0, stream>>>(Abf, Wbf, dec, w_score,
                                                    scores_p);
    softmax_kernel<<<64, 256, 0, stream>>>(scores_p, weights, context);
    context_bf16_kernel<<<512, 256, 0, stream>>>(Abf, weights, context);
  } else {
    prep_kernel<<<512, 256, 0, stream>>>(
        spatial, hidden, W_enc, b_enc, W_dec, b_dec, nullptr, nullptr, dec,
        0, 0);
    enc_score_f32_kernel<<<4096, 256, 0, stream>>>(spatial, W_enc, dec,
                                                   w_score, scores_p);
    softmax_kernel<<<64, 256, 0, stream>>>(scores_p, weights, context);
    context_f32_kernel<<<512, 256, 0, stream>>>(spatial, weights, context);
  }
}